// Round 9
// baseline (7072.970 us; speedup 1.0000x reference)
//
#include <hip/hip_runtime.h>
#include <math.h>

#define DIM 128
#define KC 1024
#define NITER 10
#define BM 128
#define BN 128
#define NB 512   // scatter blocks: n / 256

// ---- numpy-pairwise sum of squares (n=128 path), bit-exact clone ----
__global__ void sq_np_kernel(const float* __restrict__ v, float* __restrict__ out, int rows) {
    int i = blockIdx.x * blockDim.x + threadIdx.x;
    if (i >= rows) return;
    const float4* row = (const float4*)(v + (size_t)i * DIM);
    float r[8];
    {
        float4 a = row[0], b = row[1];
        r[0] = __fmul_rn(a.x, a.x); r[1] = __fmul_rn(a.y, a.y);
        r[2] = __fmul_rn(a.z, a.z); r[3] = __fmul_rn(a.w, a.w);
        r[4] = __fmul_rn(b.x, b.x); r[5] = __fmul_rn(b.y, b.y);
        r[6] = __fmul_rn(b.z, b.z); r[7] = __fmul_rn(b.w, b.w);
    }
    #pragma unroll
    for (int blk = 1; blk < 16; blk++) {
        float4 a = row[blk * 2], b = row[blk * 2 + 1];
        r[0] = __fadd_rn(r[0], __fmul_rn(a.x, a.x));
        r[1] = __fadd_rn(r[1], __fmul_rn(a.y, a.y));
        r[2] = __fadd_rn(r[2], __fmul_rn(a.z, a.z));
        r[3] = __fadd_rn(r[3], __fmul_rn(a.w, a.w));
        r[4] = __fadd_rn(r[4], __fmul_rn(b.x, b.x));
        r[5] = __fadd_rn(r[5], __fmul_rn(b.y, b.y));
        r[6] = __fadd_rn(r[6], __fmul_rn(b.z, b.z));
        r[7] = __fadd_rn(r[7], __fmul_rn(b.w, b.w));
    }
    out[i] = __fadd_rn(__fadd_rn(__fadd_rn(r[0], r[1]), __fadd_rn(r[2], r[3])),
                       __fadd_rn(__fadd_rn(r[4], r[5]), __fadd_rn(r[6], r[7])));
}

// ---- assign: fp32, sgemm-style sequential-fma dot, d=(xsq-2dot)+csq ----
// 128x128 tile, 256 threads, 8x8 micro-tile (256 fma / 16 ds_read_b128).
// LDS 128 KB (gfx950 local mem = 160 KB) -> 1 block/CU, 4 waves.
// Swizzle key (r>>3)&7: xa = 4-address broadcast (conflict-free);
// ca = 16 addresses over 8 bank-groups (2-way, free per m136).
// NUMERICS FROZEN: per-pair dot is one sequential fmaf chain, d ascending;
// score fl(fl(xsq - fl(2*dot)) + csq); argmin scan kt asc, j asc, first-min.
__global__ __launch_bounds__(256, 1) void assign_kernel(
    const float* __restrict__ x, const float* __restrict__ cent,
    const float* __restrict__ xsq, const float* __restrict__ csq,
    int* __restrict__ cl)
{
    __shared__ float4 xs[BM * 32];   // 64 KB
    __shared__ float4 cs[BN * 32];   // 64 KB
    const int tid = threadIdx.x;
    const int bm = blockIdx.x * BM;

    // stage x tile: 128 rows x 32 float4, swizzle key (r>>3)&7
    const float4* xg = (const float4*)x + (size_t)bm * 32;
    #pragma unroll
    for (int p = 0; p < 16; p++) {
        int id = tid + p * 256;
        int r = id >> 5, c4 = id & 31;
        xs[r * 32 + (c4 ^ ((r >> 3) & 7))] = xg[id];
    }

    const int ty = tid >> 4, tx = tid & 15;   // ty,tx in [0,16)
    float best[8];
    int bidx[8];
    float xq[8];
    #pragma unroll
    for (int i = 0; i < 8; i++) {
        best[i] = INFINITY; bidx[i] = 0;
        xq[i] = xsq[bm + ty * 8 + i];
    }
    const int xkey = ty & 7;   // (row>>3)&7 for rows ty*8+i (i<8)
    const int ckey = tx & 7;   // (row>>3)&7 for rows tx*8+j (j<8)

    for (int kt = 0; kt < KC / BN; kt++) {
        __syncthreads();   // WAR on cs from previous tile
        const float4* cg = (const float4*)cent + (size_t)kt * BN * 32;
        #pragma unroll
        for (int p = 0; p < 16; p++) {
            int id = tid + p * 256;
            int r = id >> 5, c4 = id & 31;
            cs[r * 32 + (c4 ^ ((r >> 3) & 7))] = cg[id];
        }
        __syncthreads();

        float acc[8][8];
        #pragma unroll
        for (int i = 0; i < 8; i++)
            #pragma unroll
            for (int j = 0; j < 8; j++) acc[i][j] = 0.f;

        #pragma unroll 2
        for (int d4 = 0; d4 < 32; d4++) {
            float4 xa[8], ca[8];
            #pragma unroll
            for (int i = 0; i < 8; i++) xa[i] = xs[(ty * 8 + i) * 32 + (d4 ^ xkey)];
            #pragma unroll
            for (int j = 0; j < 8; j++) ca[j] = cs[(tx * 8 + j) * 32 + (d4 ^ ckey)];
            #pragma unroll
            for (int i = 0; i < 8; i++)
                #pragma unroll
                for (int j = 0; j < 8; j++) {
                    acc[i][j] = fmaf(xa[i].x, ca[j].x, acc[i][j]);
                    acc[i][j] = fmaf(xa[i].y, ca[j].y, acc[i][j]);
                    acc[i][j] = fmaf(xa[i].z, ca[j].z, acc[i][j]);
                    acc[i][j] = fmaf(xa[i].w, ca[j].w, acc[i][j]);
                }
        }

        #pragma unroll
        for (int j = 0; j < 8; j++) {
            int kk = kt * BN + tx * 8 + j;
            float cq = csq[kk];
            #pragma unroll
            for (int i = 0; i < 8; i++) {
                float t = __fmul_rn(2.0f, acc[i][j]);
                float d = __fadd_rn(__fsub_rn(xq[i], t), cq);
                bool nn = (d != d);
                if ((d < best[i]) || (nn && (best[i] == best[i]))) {
                    best[i] = d; bidx[i] = kk;
                }
            }
        }
    }

    // butterfly reduce across the 16 tx lanes (same ty)
    #pragma unroll
    for (int m = 1; m < 16; m <<= 1) {
        #pragma unroll
        for (int i = 0; i < 8; i++) {
            float od = __shfl_xor(best[i], m, 64);
            int oi = __shfl_xor(bidx[i], m, 64);
            bool n1 = (best[i] != best[i]), n2 = (od != od);
            bool take;
            if (n1 && n2) take = (oi < bidx[i]);
            else if (n2) take = true;
            else if (n1) take = false;
            else take = (od < best[i]) || (od == best[i] && oi < bidx[i]);
            if (take) { best[i] = od; bidx[i] = oi; }
        }
    }
    if (tx == 0) {
        #pragma unroll
        for (int i = 0; i < 8; i++) cl[bm + ty * 8 + i] = bidx[i];
    }
}

// ---- stable counting-scatter: list[] = per-cluster ascending point index ----

__global__ __launch_bounds__(256) void bhist_kernel(const int* __restrict__ cl,
                                                    int* __restrict__ bhist, int n) {
    __shared__ int h[KC];
    int t = threadIdx.x;
    #pragma unroll
    for (int q = 0; q < KC / 256; q++) h[t + q * 256] = 0;
    __syncthreads();
    int i = blockIdx.x * 256 + t;
    if (i < n) atomicAdd(&h[cl[i]], 1);
    __syncthreads();
    int* row = bhist + (size_t)blockIdx.x * KC;
    #pragma unroll
    for (int q = 0; q < KC / 256; q++) row[t + q * 256] = h[t + q * 256];
}

__global__ __launch_bounds__(256) void colsum_kernel(const int* __restrict__ bhist,
                                                     int* __restrict__ cnt) {
    int k = blockIdx.x * 256 + threadIdx.x;
    int s = 0;
    for (int b = 0; b < NB; b++) s += bhist[(size_t)b * KC + k];
    cnt[k] = s;
}

__global__ void scan_kernel(const int* __restrict__ cnt, int* __restrict__ off) {
    __shared__ int s[KC];
    int t = threadIdx.x;
    s[t] = cnt[t];
    __syncthreads();
    for (int o = 1; o < KC; o <<= 1) {
        int v = (t >= o) ? s[t - o] : 0;
        __syncthreads();
        s[t] += v;
        __syncthreads();
    }
    off[t] = s[t] - cnt[t];
}

__global__ __launch_bounds__(256) void blockpfx_kernel(int* __restrict__ bhist,
                                                       const int* __restrict__ off) {
    int k = blockIdx.x * 256 + threadIdx.x;
    int run = off[k];
    for (int b = 0; b < NB; b++) {
        size_t idx = (size_t)b * KC + k;
        int t = bhist[idx];
        bhist[idx] = run;
        run += t;
    }
}

__global__ __launch_bounds__(256) void stable_scatter_kernel(
    const int* __restrict__ cl, const int* __restrict__ bhist,
    int* __restrict__ list, int n)
{
    __shared__ int cls[256];
    int t = threadIdx.x;
    int i = blockIdx.x * 256 + t;
    int c = (i < n) ? cl[i] : -1;
    cls[t] = c;
    __syncthreads();
    if (i >= n) return;
    int rank = 0;
    for (int j = 0; j < 256; j++)
        rank += (j < t && cls[j] == c) ? 1 : 0;
    list[bhist[(size_t)blockIdx.x * KC + c] + rank] = i;
}

// ---- segment sum: bitwise-ordered adds, latency-hidden (16-deep batches) ----
#define CHUNK 512
__global__ __launch_bounds__(128) void sum_kernel(
    const float* __restrict__ x, const int* __restrict__ list,
    const int* __restrict__ off, const int* __restrict__ cnt,
    float* __restrict__ cent, float* __restrict__ countsF)
{
    __shared__ int sidx[CHUNK];
    int k = blockIdx.x;
    int d = threadIdx.x;
    int o = off[k], m = cnt[k];
    float s = 0.f;
    for (int base = 0; base < m; base += CHUNK) {
        int c = m - base; if (c > CHUNK) c = CHUNK;
        __syncthreads();
        for (int t = d; t < c; t += 128) sidx[t] = list[o + base + t];
        __syncthreads();
        int j = 0;
        for (; j + 16 <= c; j += 16) {
            float v[16];
            #pragma unroll
            for (int u = 0; u < 16; u++)
                v[u] = x[(size_t)sidx[j + u] * DIM + d];
            #pragma unroll
            for (int u = 0; u < 16; u++)
                s = __fadd_rn(s, v[u]);
        }
        for (; j < c; j++)
            s = __fadd_rn(s, x[(size_t)sidx[j] * DIM + d]);
    }
    cent[(size_t)k * DIM + d] = __fdiv_rn(s, (float)m);  // 0/0 -> NaN, matches ref
    if (d == 0) countsF[k] = (float)m;
}

__global__ void cl2f_kernel(const int* __restrict__ cl, float* __restrict__ out, int n) {
    int i = blockIdx.x * 256 + threadIdx.x;
    if (i < n) out[i] = (float)cl[i];
}

extern "C" void kernel_launch(void* const* d_in, const int* in_sizes, int n_in,
                              void* d_out, int out_size, void* d_ws, size_t ws_size,
                              hipStream_t stream) {
    const float* x = (const float*)d_in[0];
    const int n = in_sizes[0] / DIM;  // 131072

    // d_out: [clusters (N) | centroids (K*D) | counts (K)]
    float* clf     = (float*)d_out;
    float* cent    = clf + n;
    float* countsF = cent + KC * DIM;

    // ws scratch (~3.6 MB)
    float* xsq   = (float*)d_ws;          // N
    float* csq   = xsq + n;               // K
    int*   cl    = (int*)(csq + KC);      // N
    int*   list  = cl + n;                // N
    int*   cnt   = list + n;              // K
    int*   off   = cnt + KC;              // K
    int*   bhist = off + KC;              // NB*K  (2 MB)

    hipMemcpyAsync(cent, x, (size_t)KC * DIM * sizeof(float),
                   hipMemcpyDeviceToDevice, stream);
    sq_np_kernel<<<(n + 255) / 256, 256, 0, stream>>>(x, xsq, n);

    for (int it = 0; it < NITER; it++) {
        sq_np_kernel<<<(KC + 255) / 256, 256, 0, stream>>>(cent, csq, KC);
        assign_kernel<<<n / BM, 256, 0, stream>>>(x, cent, xsq, csq, cl);
        bhist_kernel<<<NB, 256, 0, stream>>>(cl, bhist, n);
        colsum_kernel<<<KC / 256, 256, 0, stream>>>(bhist, cnt);
        scan_kernel<<<1, KC, 0, stream>>>(cnt, off);
        blockpfx_kernel<<<KC / 256, 256, 0, stream>>>(bhist, off);
        stable_scatter_kernel<<<NB, 256, 0, stream>>>(cl, bhist, list, n);
        sum_kernel<<<KC, DIM, 0, stream>>>(x, list, off, cnt, cent, countsF);
    }

    cl2f_kernel<<<(n + 255) / 256, 256, 0, stream>>>(cl, clf, n);
}

// Round 10
// 5734.930 us; speedup vs baseline: 1.2333x; 1.2333x over previous
//
#include <hip/hip_runtime.h>
#include <math.h>

#define DIM 128
#define KC 1024
#define NITER 10
#define BM 128
#define BN 128
#define NB 512   // scatter blocks: n / 256

// ---- numpy-pairwise sum of squares (n=128 path), bit-exact clone ----
__global__ void sq_np_kernel(const float* __restrict__ v, float* __restrict__ out, int rows) {
    int i = blockIdx.x * blockDim.x + threadIdx.x;
    if (i >= rows) return;
    const float4* row = (const float4*)(v + (size_t)i * DIM);
    float r[8];
    {
        float4 a = row[0], b = row[1];
        r[0] = __fmul_rn(a.x, a.x); r[1] = __fmul_rn(a.y, a.y);
        r[2] = __fmul_rn(a.z, a.z); r[3] = __fmul_rn(a.w, a.w);
        r[4] = __fmul_rn(b.x, b.x); r[5] = __fmul_rn(b.y, b.y);
        r[6] = __fmul_rn(b.z, b.z); r[7] = __fmul_rn(b.w, b.w);
    }
    #pragma unroll
    for (int blk = 1; blk < 16; blk++) {
        float4 a = row[blk * 2], b = row[blk * 2 + 1];
        r[0] = __fadd_rn(r[0], __fmul_rn(a.x, a.x));
        r[1] = __fadd_rn(r[1], __fmul_rn(a.y, a.y));
        r[2] = __fadd_rn(r[2], __fmul_rn(a.z, a.z));
        r[3] = __fadd_rn(r[3], __fmul_rn(a.w, a.w));
        r[4] = __fadd_rn(r[4], __fmul_rn(b.x, b.x));
        r[5] = __fadd_rn(r[5], __fmul_rn(b.y, b.y));
        r[6] = __fadd_rn(r[6], __fmul_rn(b.z, b.z));
        r[7] = __fadd_rn(r[7], __fmul_rn(b.w, b.w));
    }
    out[i] = __fadd_rn(__fadd_rn(__fadd_rn(r[0], r[1]), __fadd_rn(r[2], r[3])),
                       __fadd_rn(__fadd_rn(r[4], r[5]), __fadd_rn(r[6], r[7])));
}

// ---- assign: fp32, sgemm-style sequential-fma dot, d=(xsq-2dot)+csq ----
// 128x128 tile, 8x8 micro (256 fma / 16 ds_read_b128 = ratio 16), D chunked
// into two 64-dim halves so LDS = 2 x 32 KB = 64 KB -> 2 blocks/CU,
// 2 waves/SIMD (R9 post-mortem: ratio 16 at 1 wave/SIMD was latency-bound).
// x chunk re-staged per kt from L2 (block's own 64 KB -> cheap).
// Swizzle (16-col layout): key=(r>>3)&7; xa 4-addr broadcast conflict-free,
// ca 2-way (free per m136).
// NUMERICS FROZEN: per-pair dot = one sequential fmaf chain d=0..127 asc
// (acc persists across chunks); score fl(fl(xsq-fl(2dot))+csq); argmin
// first-min / first-NaN; butterfly tie -> lower index.
__global__ __launch_bounds__(256, 2) void assign_kernel(
    const float* __restrict__ x, const float* __restrict__ cent,
    const float* __restrict__ xsq, const float* __restrict__ csq,
    int* __restrict__ cl)
{
    __shared__ float4 xs[BM * 16];   // 32 KB (one 64-dim chunk)
    __shared__ float4 cs[BN * 16];   // 32 KB (one 64-dim chunk)
    const int tid = threadIdx.x;
    const int bm = blockIdx.x * BM;

    const int ty = tid >> 4, tx = tid & 15;   // ty,tx in [0,16)
    float best[8];
    int bidx[8];
    float xq[8];
    #pragma unroll
    for (int i = 0; i < 8; i++) {
        best[i] = INFINITY; bidx[i] = 0;
        xq[i] = xsq[bm + ty * 8 + i];
    }
    const int xkey = ty & 7;   // (row>>3)&7 for rows ty*8+i, i<8
    const int ckey = tx & 7;   // (row>>3)&7 for rows tx*8+j, j<8

    for (int kt = 0; kt < KC / BN; kt++) {
        float acc[8][8];
        #pragma unroll
        for (int i = 0; i < 8; i++)
            #pragma unroll
            for (int j = 0; j < 8; j++) acc[i][j] = 0.f;

        #pragma unroll
        for (int ch = 0; ch < 2; ch++) {
            __syncthreads();   // WAR: previous chunk's readers done
            // stage x chunk: 128 rows x 16 float4
            #pragma unroll
            for (int p = 0; p < 8; p++) {
                int id = tid + p * 256;
                int r = id >> 4, c4 = id & 15;
                xs[r * 16 + (c4 ^ ((r >> 3) & 7))] =
                    ((const float4*)x)[(size_t)(bm + r) * 32 + ch * 16 + c4];
            }
            // stage c chunk: 128 rows x 16 float4
            #pragma unroll
            for (int p = 0; p < 8; p++) {
                int id = tid + p * 256;
                int r = id >> 4, c4 = id & 15;
                cs[r * 16 + (c4 ^ ((r >> 3) & 7))] =
                    ((const float4*)cent)[(size_t)(kt * BN + r) * 32 + ch * 16 + c4];
            }
            __syncthreads();

            #pragma unroll 2
            for (int dd = 0; dd < 16; dd++) {
                float4 xa[8], ca[8];
                #pragma unroll
                for (int i = 0; i < 8; i++) xa[i] = xs[(ty * 8 + i) * 16 + (dd ^ xkey)];
                #pragma unroll
                for (int j = 0; j < 8; j++) ca[j] = cs[(tx * 8 + j) * 16 + (dd ^ ckey)];
                #pragma unroll
                for (int i = 0; i < 8; i++)
                    #pragma unroll
                    for (int j = 0; j < 8; j++) {
                        acc[i][j] = fmaf(xa[i].x, ca[j].x, acc[i][j]);
                        acc[i][j] = fmaf(xa[i].y, ca[j].y, acc[i][j]);
                        acc[i][j] = fmaf(xa[i].z, ca[j].z, acc[i][j]);
                        acc[i][j] = fmaf(xa[i].w, ca[j].w, acc[i][j]);
                    }
            }
        }

        #pragma unroll
        for (int j = 0; j < 8; j++) {
            int kk = kt * BN + tx * 8 + j;
            float cq = csq[kk];
            #pragma unroll
            for (int i = 0; i < 8; i++) {
                float t = __fmul_rn(2.0f, acc[i][j]);
                float d = __fadd_rn(__fsub_rn(xq[i], t), cq);
                bool nn = (d != d);
                if ((d < best[i]) || (nn && (best[i] == best[i]))) {
                    best[i] = d; bidx[i] = kk;
                }
            }
        }
    }

    // butterfly reduce across the 16 tx lanes (same ty)
    #pragma unroll
    for (int m = 1; m < 16; m <<= 1) {
        #pragma unroll
        for (int i = 0; i < 8; i++) {
            float od = __shfl_xor(best[i], m, 64);
            int oi = __shfl_xor(bidx[i], m, 64);
            bool n1 = (best[i] != best[i]), n2 = (od != od);
            bool take;
            if (n1 && n2) take = (oi < bidx[i]);
            else if (n2) take = true;
            else if (n1) take = false;
            else take = (od < best[i]) || (od == best[i] && oi < bidx[i]);
            if (take) { best[i] = od; bidx[i] = oi; }
        }
    }
    if (tx == 0) {
        #pragma unroll
        for (int i = 0; i < 8; i++) cl[bm + ty * 8 + i] = bidx[i];
    }
}

// ---- stable counting-scatter: list[] = per-cluster ascending point index ----

__global__ __launch_bounds__(256) void bhist_kernel(const int* __restrict__ cl,
                                                    int* __restrict__ bhist, int n) {
    __shared__ int h[KC];
    int t = threadIdx.x;
    #pragma unroll
    for (int q = 0; q < KC / 256; q++) h[t + q * 256] = 0;
    __syncthreads();
    int i = blockIdx.x * 256 + t;
    if (i < n) atomicAdd(&h[cl[i]], 1);
    __syncthreads();
    int* row = bhist + (size_t)blockIdx.x * KC;
    #pragma unroll
    for (int q = 0; q < KC / 256; q++) row[t + q * 256] = h[t + q * 256];
}

__global__ __launch_bounds__(256) void colsum_kernel(const int* __restrict__ bhist,
                                                     int* __restrict__ cnt) {
    int k = blockIdx.x * 256 + threadIdx.x;
    int s = 0;
    for (int b = 0; b < NB; b++) s += bhist[(size_t)b * KC + k];
    cnt[k] = s;
}

__global__ void scan_kernel(const int* __restrict__ cnt, int* __restrict__ off) {
    __shared__ int s[KC];
    int t = threadIdx.x;
    s[t] = cnt[t];
    __syncthreads();
    for (int o = 1; o < KC; o <<= 1) {
        int v = (t >= o) ? s[t - o] : 0;
        __syncthreads();
        s[t] += v;
        __syncthreads();
    }
    off[t] = s[t] - cnt[t];
}

__global__ __launch_bounds__(256) void blockpfx_kernel(int* __restrict__ bhist,
                                                       const int* __restrict__ off) {
    int k = blockIdx.x * 256 + threadIdx.x;
    int run = off[k];
    for (int b = 0; b < NB; b++) {
        size_t idx = (size_t)b * KC + k;
        int t = bhist[idx];
        bhist[idx] = run;
        run += t;
    }
}

__global__ __launch_bounds__(256) void stable_scatter_kernel(
    const int* __restrict__ cl, const int* __restrict__ bhist,
    int* __restrict__ list, int n)
{
    __shared__ int cls[256];
    int t = threadIdx.x;
    int i = blockIdx.x * 256 + t;
    int c = (i < n) ? cl[i] : -1;
    cls[t] = c;
    __syncthreads();
    if (i >= n) return;
    int rank = 0;
    for (int j = 0; j < 256; j++)
        rank += (j < t && cls[j] == c) ? 1 : 0;
    list[bhist[(size_t)blockIdx.x * KC + c] + rank] = i;
}

// ---- segment sum: bitwise-ordered adds, latency-hidden (16-deep batches) ----
#define CHUNK 512
__global__ __launch_bounds__(128) void sum_kernel(
    const float* __restrict__ x, const int* __restrict__ list,
    const int* __restrict__ off, const int* __restrict__ cnt,
    float* __restrict__ cent, float* __restrict__ countsF)
{
    __shared__ int sidx[CHUNK];
    int k = blockIdx.x;
    int d = threadIdx.x;
    int o = off[k], m = cnt[k];
    float s = 0.f;
    for (int base = 0; base < m; base += CHUNK) {
        int c = m - base; if (c > CHUNK) c = CHUNK;
        __syncthreads();
        for (int t = d; t < c; t += 128) sidx[t] = list[o + base + t];
        __syncthreads();
        int j = 0;
        for (; j + 16 <= c; j += 16) {
            float v[16];
            #pragma unroll
            for (int u = 0; u < 16; u++)
                v[u] = x[(size_t)sidx[j + u] * DIM + d];
            #pragma unroll
            for (int u = 0; u < 16; u++)
                s = __fadd_rn(s, v[u]);
        }
        for (; j < c; j++)
            s = __fadd_rn(s, x[(size_t)sidx[j] * DIM + d]);
    }
    cent[(size_t)k * DIM + d] = __fdiv_rn(s, (float)m);  // 0/0 -> NaN, matches ref
    if (d == 0) countsF[k] = (float)m;
}

__global__ void cl2f_kernel(const int* __restrict__ cl, float* __restrict__ out, int n) {
    int i = blockIdx.x * 256 + threadIdx.x;
    if (i < n) out[i] = (float)cl[i];
}

extern "C" void kernel_launch(void* const* d_in, const int* in_sizes, int n_in,
                              void* d_out, int out_size, void* d_ws, size_t ws_size,
                              hipStream_t stream) {
    const float* x = (const float*)d_in[0];
    const int n = in_sizes[0] / DIM;  // 131072

    // d_out: [clusters (N) | centroids (K*D) | counts (K)]
    float* clf     = (float*)d_out;
    float* cent    = clf + n;
    float* countsF = cent + KC * DIM;

    // ws scratch (~3.6 MB)
    float* xsq   = (float*)d_ws;          // N
    float* csq   = xsq + n;               // K
    int*   cl    = (int*)(csq + KC);      // N
    int*   list  = cl + n;                // N
    int*   cnt   = list + n;              // K
    int*   off   = cnt + KC;              // K
    int*   bhist = off + KC;              // NB*K  (2 MB)

    hipMemcpyAsync(cent, x, (size_t)KC * DIM * sizeof(float),
                   hipMemcpyDeviceToDevice, stream);
    sq_np_kernel<<<(n + 255) / 256, 256, 0, stream>>>(x, xsq, n);

    for (int it = 0; it < NITER; it++) {
        sq_np_kernel<<<(KC + 255) / 256, 256, 0, stream>>>(cent, csq, KC);
        assign_kernel<<<n / BM, 256, 0, stream>>>(x, cent, xsq, csq, cl);
        bhist_kernel<<<NB, 256, 0, stream>>>(cl, bhist, n);
        colsum_kernel<<<KC / 256, 256, 0, stream>>>(bhist, cnt);
        scan_kernel<<<1, KC, 0, stream>>>(cnt, off);
        blockpfx_kernel<<<KC / 256, 256, 0, stream>>>(bhist, off);
        stable_scatter_kernel<<<NB, 256, 0, stream>>>(cl, bhist, list, n);
        sum_kernel<<<KC, DIM, 0, stream>>>(x, list, off, cnt, cent, countsF);
    }

    cl2f_kernel<<<(n + 255) / 256, 256, 0, stream>>>(cl, clf, n);
}

// Round 11
// 5393.830 us; speedup vs baseline: 1.3113x; 1.0632x over previous
//
#include <hip/hip_runtime.h>
#include <math.h>

#define DIM 128
#define KC 1024
#define NITER 10
#define BM 128
#define BN 128
#define NB 512   // scatter blocks: n / 256

// ---- numpy-pairwise sum of squares (n=128 path), bit-exact clone ----
__global__ void sq_np_kernel(const float* __restrict__ v, float* __restrict__ out, int rows) {
    int i = blockIdx.x * blockDim.x + threadIdx.x;
    if (i >= rows) return;
    const float4* row = (const float4*)(v + (size_t)i * DIM);
    float r[8];
    {
        float4 a = row[0], b = row[1];
        r[0] = __fmul_rn(a.x, a.x); r[1] = __fmul_rn(a.y, a.y);
        r[2] = __fmul_rn(a.z, a.z); r[3] = __fmul_rn(a.w, a.w);
        r[4] = __fmul_rn(b.x, b.x); r[5] = __fmul_rn(b.y, b.y);
        r[6] = __fmul_rn(b.z, b.z); r[7] = __fmul_rn(b.w, b.w);
    }
    #pragma unroll
    for (int blk = 1; blk < 16; blk++) {
        float4 a = row[blk * 2], b = row[blk * 2 + 1];
        r[0] = __fadd_rn(r[0], __fmul_rn(a.x, a.x));
        r[1] = __fadd_rn(r[1], __fmul_rn(a.y, a.y));
        r[2] = __fadd_rn(r[2], __fmul_rn(a.z, a.z));
        r[3] = __fadd_rn(r[3], __fmul_rn(a.w, a.w));
        r[4] = __fadd_rn(r[4], __fmul_rn(b.x, b.x));
        r[5] = __fadd_rn(r[5], __fmul_rn(b.y, b.y));
        r[6] = __fadd_rn(r[6], __fmul_rn(b.z, b.z));
        r[7] = __fadd_rn(r[7], __fmul_rn(b.w, b.w));
    }
    out[i] = __fadd_rn(__fadd_rn(__fadd_rn(r[0], r[1]), __fadd_rn(r[2], r[3])),
                       __fadd_rn(__fadd_rn(r[4], r[5]), __fadd_rn(r[6], r[7])));
}

// ---- assign: fp32, sgemm-style sequential-fma dot, d=(xsq-2dot)+csq ----
// R11 structure: x-tile (128x128, 64 KB) staged in LDS ONCE (no K-loop
// barriers); centroids read straight from global in transposed centT[D][K]
// layout (L2-resident, 16 tx lanes x 16 B = 256 B contiguous per inst).
// LDS reads are xa only: 4-address broadcast, conflict-free -> LDS traffic
// halved and SQ_LDS_BANK_CONFLICT ~0. 2 blocks/CU (2 waves/SIMD).
// Thread's 8 cents: {tx*4+q, 64+tx*4+q} (kk ascending within thread).
// NUMERICS FROZEN: per-pair dot = one sequential fmaf chain d=0..127 asc;
// score fl(fl(xsq-fl(2dot))+csq); argmin first-min / first-NaN;
// butterfly tie -> lower index.
__global__ __launch_bounds__(256, 2) void assign_kernel(
    const float* __restrict__ x, const float* __restrict__ centT,
    const float* __restrict__ xsq, const float* __restrict__ csq,
    int* __restrict__ cl)
{
    __shared__ float4 xs[BM * 32];   // 64 KB, full 128 dims
    const int tid = threadIdx.x;
    const int bm = blockIdx.x * BM;

    // stage x tile once: 128 rows x 32 float4, swizzle key (r>>3)&7
    const float4* xg = (const float4*)x + (size_t)bm * 32;
    #pragma unroll
    for (int p = 0; p < 16; p++) {
        int id = tid + p * 256;
        int r = id >> 5, c4 = id & 31;
        xs[r * 32 + (c4 ^ ((r >> 3) & 7))] = xg[id];
    }
    __syncthreads();   // the only barrier: xs is read-only afterwards

    const int ty = tid >> 4, tx = tid & 15;
    const int xkey = ty & 7;   // (r>>3)&7 for rows ty*8+i, i<8
    float best[8];
    int bidx[8];
    float xq[8];
    #pragma unroll
    for (int i = 0; i < 8; i++) {
        best[i] = INFINITY; bidx[i] = 0;
        xq[i] = xsq[bm + ty * 8 + i];
    }

    for (int kt = 0; kt < KC / BN; kt++) {
        float acc[8][8];
        #pragma unroll
        for (int i = 0; i < 8; i++)
            #pragma unroll
            for (int j = 0; j < 8; j++) acc[i][j] = 0.f;

        const float* cb = centT + kt * BN;   // + d*KC per dim row

        #pragma unroll 4
        for (int dd = 0; dd < 32; dd++) {
            float4 xa[8];
            #pragma unroll
            for (int i = 0; i < 8; i++)
                xa[i] = xs[(ty * 8 + i) * 32 + (dd ^ xkey)];

            const float* r0 = cb + (size_t)(dd * 4 + 0) * KC;
            const float* r1 = cb + (size_t)(dd * 4 + 1) * KC;
            const float* r2 = cb + (size_t)(dd * 4 + 2) * KC;
            const float* r3 = cb + (size_t)(dd * 4 + 3) * KC;
            float4 A0 = *(const float4*)(r0 + tx * 4);
            float4 A1 = *(const float4*)(r1 + tx * 4);
            float4 A2 = *(const float4*)(r2 + tx * 4);
            float4 A3 = *(const float4*)(r3 + tx * 4);
            float4 B0 = *(const float4*)(r0 + 64 + tx * 4);
            float4 B1 = *(const float4*)(r1 + 64 + tx * 4);
            float4 B2 = *(const float4*)(r2 + 64 + tx * 4);
            float4 B3 = *(const float4*)(r3 + 64 + tx * 4);

            #pragma unroll
            for (int i = 0; i < 8; i++) {
                float4 xv = xa[i];
                // dims dd*4+0..3 ascending per (i,j) -- frozen chain order
#define FMA4(J, C0, C1, C2, C3)                          \
                acc[i][J] = fmaf(xv.x, C0, acc[i][J]);   \
                acc[i][J] = fmaf(xv.y, C1, acc[i][J]);   \
                acc[i][J] = fmaf(xv.z, C2, acc[i][J]);   \
                acc[i][J] = fmaf(xv.w, C3, acc[i][J]);
                FMA4(0, A0.x, A1.x, A2.x, A3.x)
                FMA4(1, A0.y, A1.y, A2.y, A3.y)
                FMA4(2, A0.z, A1.z, A2.z, A3.z)
                FMA4(3, A0.w, A1.w, A2.w, A3.w)
                FMA4(4, B0.x, B1.x, B2.x, B3.x)
                FMA4(5, B0.y, B1.y, B2.y, B3.y)
                FMA4(6, B0.z, B1.z, B2.z, B3.z)
                FMA4(7, B0.w, B1.w, B2.w, B3.w)
#undef FMA4
            }
        }

        #pragma unroll
        for (int j = 0; j < 8; j++) {
            int kk = kt * BN + ((j < 4) ? (tx * 4 + j) : (64 + tx * 4 + (j - 4)));
            float cq = csq[kk];
            #pragma unroll
            for (int i = 0; i < 8; i++) {
                float t = __fmul_rn(2.0f, acc[i][j]);
                float d = __fadd_rn(__fsub_rn(xq[i], t), cq);
                bool nn = (d != d);
                if ((d < best[i]) || (nn && (best[i] == best[i]))) {
                    best[i] = d; bidx[i] = kk;
                }
            }
        }
    }

    // butterfly reduce across the 16 tx lanes (same ty)
    #pragma unroll
    for (int m = 1; m < 16; m <<= 1) {
        #pragma unroll
        for (int i = 0; i < 8; i++) {
            float od = __shfl_xor(best[i], m, 64);
            int oi = __shfl_xor(bidx[i], m, 64);
            bool n1 = (best[i] != best[i]), n2 = (od != od);
            bool take;
            if (n1 && n2) take = (oi < bidx[i]);
            else if (n2) take = true;
            else if (n1) take = false;
            else take = (od < best[i]) || (od == best[i] && oi < bidx[i]);
            if (take) { best[i] = od; bidx[i] = oi; }
        }
    }
    if (tx == 0) {
        #pragma unroll
        for (int i = 0; i < 8; i++) cl[bm + ty * 8 + i] = bidx[i];
    }
}

// ---- stable counting-scatter: list[] = per-cluster ascending point index ----

__global__ __launch_bounds__(256) void bhist_kernel(const int* __restrict__ cl,
                                                    int* __restrict__ bhist, int n) {
    __shared__ int h[KC];
    int t = threadIdx.x;
    #pragma unroll
    for (int q = 0; q < KC / 256; q++) h[t + q * 256] = 0;
    __syncthreads();
    int i = blockIdx.x * 256 + t;
    if (i < n) atomicAdd(&h[cl[i]], 1);
    __syncthreads();
    int* row = bhist + (size_t)blockIdx.x * KC;
    #pragma unroll
    for (int q = 0; q < KC / 256; q++) row[t + q * 256] = h[t + q * 256];
}

__global__ __launch_bounds__(256) void colsum_kernel(const int* __restrict__ bhist,
                                                     int* __restrict__ cnt) {
    int k = blockIdx.x * 256 + threadIdx.x;
    int s = 0;
    for (int b = 0; b < NB; b++) s += bhist[(size_t)b * KC + k];
    cnt[k] = s;
}

__global__ void scan_kernel(const int* __restrict__ cnt, int* __restrict__ off) {
    __shared__ int s[KC];
    int t = threadIdx.x;
    s[t] = cnt[t];
    __syncthreads();
    for (int o = 1; o < KC; o <<= 1) {
        int v = (t >= o) ? s[t - o] : 0;
        __syncthreads();
        s[t] += v;
        __syncthreads();
    }
    off[t] = s[t] - cnt[t];
}

__global__ __launch_bounds__(256) void blockpfx_kernel(int* __restrict__ bhist,
                                                       const int* __restrict__ off) {
    int k = blockIdx.x * 256 + threadIdx.x;
    int run = off[k];
    for (int b = 0; b < NB; b++) {
        size_t idx = (size_t)b * KC + k;
        int t = bhist[idx];
        bhist[idx] = run;
        run += t;
    }
}

__global__ __launch_bounds__(256) void stable_scatter_kernel(
    const int* __restrict__ cl, const int* __restrict__ bhist,
    int* __restrict__ list, int n)
{
    __shared__ int cls[256];
    int t = threadIdx.x;
    int i = blockIdx.x * 256 + t;
    int c = (i < n) ? cl[i] : -1;
    cls[t] = c;
    __syncthreads();
    if (i >= n) return;
    int rank = 0;
    for (int j = 0; j < 256; j++)
        rank += (j < t && cls[j] == c) ? 1 : 0;
    list[bhist[(size_t)blockIdx.x * KC + c] + rank] = i;
}

// ---- segment sum: bitwise-ordered adds, latency-hidden; also maintains
// the transposed centT[D][K] consumed by assign_kernel ----
#define CHUNK 512
__global__ __launch_bounds__(128) void sum_kernel(
    const float* __restrict__ x, const int* __restrict__ list,
    const int* __restrict__ off, const int* __restrict__ cnt,
    float* __restrict__ cent, float* __restrict__ centT,
    float* __restrict__ countsF)
{
    __shared__ int sidx[CHUNK];
    int k = blockIdx.x;
    int d = threadIdx.x;
    int o = off[k], m = cnt[k];
    float s = 0.f;
    for (int base = 0; base < m; base += CHUNK) {
        int c = m - base; if (c > CHUNK) c = CHUNK;
        __syncthreads();
        for (int t = d; t < c; t += 128) sidx[t] = list[o + base + t];
        __syncthreads();
        int j = 0;
        for (; j + 16 <= c; j += 16) {
            float v[16];
            #pragma unroll
            for (int u = 0; u < 16; u++)
                v[u] = x[(size_t)sidx[j + u] * DIM + d];
            #pragma unroll
            for (int u = 0; u < 16; u++)
                s = __fadd_rn(s, v[u]);
        }
        for (; j < c; j++)
            s = __fadd_rn(s, x[(size_t)sidx[j] * DIM + d]);
    }
    float mv = __fdiv_rn(s, (float)m);   // 0/0 -> NaN, matches ref
    cent[(size_t)k * DIM + d] = mv;
    centT[(size_t)d * KC + k] = mv;
    if (d == 0) countsF[k] = (float)m;
}

__global__ void init_centT_kernel(const float* __restrict__ x, float* __restrict__ centT) {
    int i = blockIdx.x * 256 + threadIdx.x;
    if (i < KC * DIM) {
        int k = i >> 7, d = i & 127;
        centT[(size_t)d * KC + k] = x[i];
    }
}

__global__ void cl2f_kernel(const int* __restrict__ cl, float* __restrict__ out, int n) {
    int i = blockIdx.x * 256 + threadIdx.x;
    if (i < n) out[i] = (float)cl[i];
}

extern "C" void kernel_launch(void* const* d_in, const int* in_sizes, int n_in,
                              void* d_out, int out_size, void* d_ws, size_t ws_size,
                              hipStream_t stream) {
    const float* x = (const float*)d_in[0];
    const int n = in_sizes[0] / DIM;  // 131072

    // d_out: [clusters (N) | centroids (K*D) | counts (K)]
    float* clf     = (float*)d_out;
    float* cent    = clf + n;
    float* countsF = cent + KC * DIM;

    // ws scratch (~4.1 MB; 3.7 MB verified safe in R3)
    float* xsq   = (float*)d_ws;          // N
    float* csq   = xsq + n;               // K
    int*   cl    = (int*)(csq + KC);      // N
    int*   list  = cl + n;                // N
    int*   cnt   = list + n;              // K
    int*   off   = cnt + KC;              // K
    int*   bhist = off + KC;              // NB*K  (2 MB)
    float* centT = (float*)(bhist + (size_t)NB * KC);  // K*D (512 KB), [D][K]

    hipMemcpyAsync(cent, x, (size_t)KC * DIM * sizeof(float),
                   hipMemcpyDeviceToDevice, stream);
    init_centT_kernel<<<(KC * DIM + 255) / 256, 256, 0, stream>>>(x, centT);
    sq_np_kernel<<<(n + 255) / 256, 256, 0, stream>>>(x, xsq, n);

    for (int it = 0; it < NITER; it++) {
        sq_np_kernel<<<(KC + 255) / 256, 256, 0, stream>>>(cent, csq, KC);
        assign_kernel<<<n / BM, 256, 0, stream>>>(x, centT, xsq, csq, cl);
        bhist_kernel<<<NB, 256, 0, stream>>>(cl, bhist, n);
        colsum_kernel<<<KC / 256, 256, 0, stream>>>(bhist, cnt);
        scan_kernel<<<1, KC, 0, stream>>>(cnt, off);
        blockpfx_kernel<<<KC / 256, 256, 0, stream>>>(bhist, off);
        stable_scatter_kernel<<<NB, 256, 0, stream>>>(cl, bhist, list, n);
        sum_kernel<<<KC, DIM, 0, stream>>>(x, list, off, cnt, cent, centT, countsF);
    }

    cl2f_kernel<<<(n + 255) / 256, 256, 0, stream>>>(cl, clf, n);
}